// Round 5
// baseline (225.113 us; speedup 1.0000x reference)
//
#include <hip/hip_runtime.h>

// LSTM (B=8192, T=512, H=5) + MLP 5->32->32->5, fp32.
// Round 14: cut serial transcendental positions 4 -> 2.
//  - R9..R13 post-mortem: wall pinned at 485-500 cyc/step through every
//    instruction diet; only chain-latency additions moved it. Fit:
//    485 ~= dots + 4*L_trans + ALU + DPP with L_trans ~= 90-100 at
//    1 wave/SIMD. The 4 SERIAL trans positions (exp2 -> rcp -> exp2 ->
//    rcp) are the floor. R13's rcp-combines removed parallel trans,
//    not serial positions -> no change (confirmed).
//  - Fix: sign-symmetry. sigma(p), tanh(p) need only e^{-|.|}, so every
//    denominator A = 1+e^{-|.|} is in [1,2]: replace ALL hw rcps with
//    cubic seed + 1 Newton (pure FMA, chain ~24 vs ~90). Chebyshev cubic
//    for 1/A on [1,2], verified at A=1,1.25,1.5,2 (|err|<=1.5e-3; after
//    Newton <=2.2e-6). -|z| is a free VOP3 modifier on v_exp_f32.
//    Serial chain: dots -> exp2(4 par) -> inv(FMA) -> c -> exp2 ->
//    inv(FMA) -> h -> DPP. Also kills the 2^43 overflow concern.
//  - Gate recovery: sigma(p) = (z<=0) ? r : 1-r (z = -LOG2E*p);
//    tanh via |.|: th = sgn XOR (2r-1); h = og*(2rc-1) XOR sgn(c).
//  - Keeps: zx 2-deep pipeline + fenced fillers (R13), freed allocator
//    (R10), DPP broadcast (R9), LDS x-staging RSTR=164 (R8).

#define LOG2E 1.44269504088896f

__device__ __forceinline__ float hexp2(float x) { return __builtin_amdgcn_exp2f(x); }
#define SBAR() __builtin_amdgcn_sched_barrier(0)

// 1/A on [1,2]: Chebyshev cubic seed + 1 Newton. err <= ~2.2e-6.
__device__ __forceinline__ float inv12(float A) {
  const float C0 =  2.8498746f, C1 = -2.9843788f,
              C2 =  1.3615900f, C3 = -0.2285656f;
  float A2 = A * A;
  float lo = fmaf(A, C1, C0);
  float hi = fmaf(A, C3, C2);
  float r0 = fmaf(A2, hi, lo);
  float t  = fmaf(-A, r0, 2.0f);
  return r0 * t;
}

template<int CTRL>
__device__ __forceinline__ float dpp_mov(float x) {
  int r = __builtin_amdgcn_update_dpp(0, __builtin_bit_cast(int, x),
                                      CTRL, 0xF, 0xF, true);
  return __builtin_bit_cast(float, r);
}
template<int CTRL, int BANKMASK>
__device__ __forceinline__ float dpp_merge(float old, float src) {
  int r = __builtin_amdgcn_update_dpp(__builtin_bit_cast(int, old),
                                      __builtin_bit_cast(int, src),
                                      CTRL, 0xF, BANKMASK, false);
  return __builtin_bit_cast(float, r);
}

constexpr int TT   = 512;
constexpr int HD   = 5;
constexpr int RPB  = 8;     // rows per wave (8 lanes each)
constexpr int CHNK = 32;    // steps per LDS chunk
constexpr int RSTR = 164;   // padded LDS row stride
constexpr int XOFF = RPB * RSTR;
constexpr int NCH  = TT / CHNK;

__global__ __attribute__((amdgpu_flat_work_group_size(64, 64),
                          amdgpu_waves_per_eu(1, 1)))
void lstm_mlp_kernel(
    const float* __restrict__ x,   const float* __restrict__ Wih,
    const float* __restrict__ Whh, const float* __restrict__ bih,
    const float* __restrict__ bhh, const float* __restrict__ W1,
    const float* __restrict__ b1,  const float* __restrict__ W2,
    const float* __restrict__ b2,  const float* __restrict__ W3,
    const float* __restrict__ b3,  float* __restrict__ out, int B)
{
  const int lane = threadIdx.x;
  const int grp  = lane >> 3;           // row within block (0..7)
  const int j    = lane & 7;            // unit owned (valid if j<5)
  const int jj   = (j < 5) ? j : 0;
  const int blockRow = blockIdx.x * RPB;
  const int row  = blockRow + grp;
  const bool act = (j < 5) && (row < B);

  __shared__ __align__(16) float xbuf[2 * XOFF];
  __shared__ float s1[RPB][32];
  __shared__ float s2[RPB][32];

  // ---- per-lane weights (rows {j,5+j,10+j,15+j}), activation pre-scaled --
  float wih[4][5], whh[4][5], bsum[4];
#pragma unroll
  for (int G = 0; G < 4; ++G) {
    const float sc = (G == 2) ? (2.0f * LOG2E) : (-LOG2E);
#pragma unroll
    for (int k = 0; k < 5; ++k) {
      wih[G][k] = Wih[(G * 5 + jj) * 5 + k] * sc;
      whh[G][k] = Whh[(G * 5 + jj) * 5 + k] * sc;
    }
    bsum[G] = (bih[G * 5 + jj] + bhh[G * 5 + jj]) * sc;
  }

  const int rowc = (row < B) ? row : (B - 1);
  const float xl0 = x[(size_t)rowc * (TT * HD) + 511 * HD + 0];
  const float xl1 = x[(size_t)rowc * (TT * HD) + 511 * HD + 1];
  const float xl2 = x[(size_t)rowc * (TT * HD) + 511 * HD + 2];
  const float xl3 = x[(size_t)rowc * (TT * HD) + 511 * HD + 3];
  const float xl4 = x[(size_t)rowc * (TT * HD) + 511 * HD + 4];

  // ---- staging: 5x16B per lane per 32-step chunk (R8-proven) ----
  const float4* gp[5];
  int wa[5];
#pragma unroll
  for (int i = 0; i < 5; ++i) {
    int u  = i * 64 + lane;
    int r  = u / 40;
    int o4 = u - r * 40;
    int gr = blockRow + r; if (gr >= B) gr = B - 1;
    gp[i]  = (const float4*)(x + (size_t)gr * (TT * HD)) + o4;
    wa[i]  = r * RSTR + o4 * 4;
  }

  float4 st0, st1, st2, st3, st4;
  st0 = *gp[0]; gp[0] += 40; st1 = *gp[1]; gp[1] += 40;
  st2 = *gp[2]; gp[2] += 40; st3 = *gp[3]; gp[3] += 40;
  st4 = *gp[4]; gp[4] += 40;
  *(float4*)&xbuf[wa[0]] = st0; *(float4*)&xbuf[wa[1]] = st1;
  *(float4*)&xbuf[wa[2]] = st2; *(float4*)&xbuf[wa[3]] = st3;
  *(float4*)&xbuf[wa[4]] = st4;
  st0 = *gp[0]; gp[0] += 40; st1 = *gp[1]; gp[1] += 40;
  st2 = *gp[2]; gp[2] += 40; st3 = *gp[3]; gp[3] += 40;
  st4 = *gp[4]; gp[4] += 40;

  // ---- recurrence state ----
  float c = 0.0f;
  float hv0 = 0.f, hv1 = 0.f, hv2 = 0.f, hv3 = 0.f, hv4 = 0.f;
  // 2-deep x-part queue: zxA = current step, zxB = next step
  float zxA0, zxA1, zxA2, zxA3;
  float zxB0, zxB1, zxB2, zxB3;

  // prologue: zx for steps 0 and 1 from the just-written chunk-0 buffer
  {
    const float* xp = &xbuf[grp * RSTR];
#pragma unroll
    for (int s = 0; s < 2; ++s) {
      float p0 = xp[5*s+0], p1 = xp[5*s+1], p2 = xp[5*s+2],
            p3 = xp[5*s+3], p4 = xp[5*s+4];
      float t0 = bsum[0], t1 = bsum[1], t2 = bsum[2], t3 = bsum[3];
      t0 = fmaf(p0, wih[0][0], t0); t0 = fmaf(p1, wih[0][1], t0);
      t0 = fmaf(p2, wih[0][2], t0); t0 = fmaf(p3, wih[0][3], t0);
      t0 = fmaf(p4, wih[0][4], t0);
      t1 = fmaf(p0, wih[1][0], t1); t1 = fmaf(p1, wih[1][1], t1);
      t1 = fmaf(p2, wih[1][2], t1); t1 = fmaf(p3, wih[1][3], t1);
      t1 = fmaf(p4, wih[1][4], t1);
      t2 = fmaf(p0, wih[2][0], t2); t2 = fmaf(p1, wih[2][1], t2);
      t2 = fmaf(p2, wih[2][2], t2); t2 = fmaf(p3, wih[2][3], t2);
      t2 = fmaf(p4, wih[2][4], t2);
      t3 = fmaf(p0, wih[3][0], t3); t3 = fmaf(p1, wih[3][1], t3);
      t3 = fmaf(p2, wih[3][2], t3); t3 = fmaf(p3, wih[3][3], t3);
      t3 = fmaf(p4, wih[3][4], t3);
      if (s == 0) { zxA0 = t0; zxA1 = t1; zxA2 = t2; zxA3 = t3; }
      else        { zxB0 = t0; zxB1 = t1; zxB2 = t2; zxB3 = t3; }
    }
  }

  // fenced pipelined step: consumes zxA (step t), computes x-part of
  // step t+2 from n0..n4 inside t's latency windows.
  auto stepP = [&](float n0, float n1, float n2, float n3, float n4) {
    // P1: h-dots (chain head), order bias->x (in zx) ->h0..h4 preserved
    float z0 = zxA0, z1 = zxA1, z2 = zxA2, z3 = zxA3;
    z0 = fmaf(hv0, whh[0][0], z0); z0 = fmaf(hv1, whh[0][1], z0);
    z0 = fmaf(hv2, whh[0][2], z0); z0 = fmaf(hv3, whh[0][3], z0);
    z0 = fmaf(hv4, whh[0][4], z0);
    z1 = fmaf(hv0, whh[1][0], z1); z1 = fmaf(hv1, whh[1][1], z1);
    z1 = fmaf(hv2, whh[1][2], z1); z1 = fmaf(hv3, whh[1][3], z1);
    z1 = fmaf(hv4, whh[1][4], z1);
    z2 = fmaf(hv0, whh[2][0], z2); z2 = fmaf(hv1, whh[2][1], z2);
    z2 = fmaf(hv2, whh[2][2], z2); z2 = fmaf(hv3, whh[2][3], z2);
    z2 = fmaf(hv4, whh[2][4], z2);
    z3 = fmaf(hv0, whh[3][0], z3); z3 = fmaf(hv1, whh[3][1], z3);
    z3 = fmaf(hv2, whh[3][2], z3); z3 = fmaf(hv3, whh[3][3], z3);
    z3 = fmaf(hv4, whh[3][4], z3);
    // P2: 4 parallel exp2 of -|z| (free VOP3 source modifiers)
    float e2 = hexp2(-__builtin_fabsf(z2));
    float e0 = hexp2(-__builtin_fabsf(z0));
    float e1 = hexp2(-__builtin_fabsf(z1));
    float e3 = hexp2(-__builtin_fabsf(z3));
    SBAR();
    // F1: x-part(t+2) gates 0,1 — fills exp latency
    float n_0 = bsum[0];
    n_0 = fmaf(n0, wih[0][0], n_0); n_0 = fmaf(n1, wih[0][1], n_0);
    n_0 = fmaf(n2, wih[0][2], n_0); n_0 = fmaf(n3, wih[0][3], n_0);
    n_0 = fmaf(n4, wih[0][4], n_0);
    float n_1 = bsum[1];
    n_1 = fmaf(n0, wih[1][0], n_1); n_1 = fmaf(n1, wih[1][1], n_1);
    n_1 = fmaf(n2, wih[1][2], n_1); n_1 = fmaf(n3, wih[1][3], n_1);
    n_1 = fmaf(n4, wih[1][4], n_1);
    SBAR();
    // P3: denominators in [1,2] + 4 parallel FMA-inverses
    float Ai = 1.0f + e0;
    float Af = 1.0f + e1;
    float Ag = 1.0f + e2;
    float Ao = 1.0f + e3;
    float ri = inv12(Ai);     // sigma(|p|)
    float rf = inv12(Af);
    float rg = inv12(Ag);     // sigma(2|p_g|)
    float ro = inv12(Ao);
    SBAR();
    // F2: x-part(t+2) gate 2 — fills inv chain
    float n_2 = bsum[2];
    n_2 = fmaf(n0, wih[2][0], n_2); n_2 = fmaf(n1, wih[2][1], n_2);
    n_2 = fmaf(n2, wih[2][2], n_2); n_2 = fmaf(n3, wih[2][3], n_2);
    n_2 = fmaf(n4, wih[2][4], n_2);
    SBAR();
    // P4: gate recovery + c-update + exp2(c)
    // z = -LOG2E*p for gates 0,1,3: p>=0 <=> z<=0
    float ig = (z0 <= 0.0f) ? ri : 1.0f - ri;
    float fg = (z1 <= 0.0f) ? rf : 1.0f - rf;
    float og = (z3 <= 0.0f) ? ro : 1.0f - ro;
    // g = tanh(p_g): z2 = +2LOG2E*p_g; |tanh| = 2*rg-1, sign = sign(z2)
    float gm = fmaf(2.0f, rg, -1.0f);
    int   sg = __builtin_bit_cast(int, z2) & 0x80000000;
    float gv = __builtin_bit_cast(float, __builtin_bit_cast(int, gm) ^ sg);
    c = fmaf(fg, c, ig * gv);
    float ec = hexp2(-2.0f * LOG2E * __builtin_fabsf(c));
    SBAR();
    // F3: x-part(t+2) gate 3 — fills exp2(c) latency
    float n_3 = bsum[3];
    n_3 = fmaf(n0, wih[3][0], n_3); n_3 = fmaf(n1, wih[3][1], n_3);
    n_3 = fmaf(n2, wih[3][2], n_3); n_3 = fmaf(n3, wih[3][3], n_3);
    n_3 = fmaf(n4, wih[3][4], n_3);
    SBAR();
    // P5: tanh(c) via FMA-inverse; h = og*|th| with sign of c
    float Ac = 1.0f + ec;
    float rc = inv12(Ac);
    float thm = fmaf(2.0f, rc, -1.0f);   // |tanh(c)|
    float hm  = og * thm;
    int   sc_ = __builtin_bit_cast(int, c) & 0x80000000;
    float h   = __builtin_bit_cast(float, __builtin_bit_cast(int, hm) ^ sc_);
    // P6: broadcast (R9-proven)
    float q0 = dpp_mov<0x00>(h);
    float q1 = dpp_mov<0x55>(h);
    float q2 = dpp_mov<0xAA>(h);
    float q3 = dpp_mov<0xFF>(h);
    hv0 = dpp_merge<0x114, 0xA>(q0, q0);
    hv1 = dpp_merge<0x114, 0xA>(q1, q1);
    hv2 = dpp_merge<0x114, 0xA>(q2, q2);
    hv3 = dpp_merge<0x114, 0xA>(q3, q3);
    hv4 = dpp_merge<0x104, 0x5>(q0, q0);
    // rotate the zx queue
    zxA0 = zxB0; zxA1 = zxB1; zxA2 = zxB2; zxA3 = zxB3;
    zxB0 = n_0;  zxB1 = n_1;  zxB2 = n_2;  zxB3 = n_3;
  };

  float4 A0v, A1v, A2v, A3v, A4v;
  float4 B0v, B1v, B2v, B3v, B4v;

  auto rdg = [&](int fi, float4& Av, float4& Bv, float4& Cv, float4& Dv, float4& Ev) {
    const float4* p = (const float4*)&xbuf[fi];
    Av = p[0]; Bv = p[1]; Cv = p[2]; Dv = p[3]; Ev = p[4];
  };

  // SUBA: steps a..a+3; fillers = x(a+2..a+5)
  auto SUBA = [&]() {
    stepP(A2v.z, A2v.w, A3v.x, A3v.y, A3v.z);
    stepP(A3v.w, A4v.x, A4v.y, A4v.z, A4v.w);
    stepP(B0v.x, B0v.y, B0v.z, B0v.w, B1v.x);
    stepP(B1v.y, B1v.z, B1v.w, B2v.x, B2v.y);
  };
  // SUBB: steps b..b+3; fillers = x(b+2..b+5)
  auto SUBB = [&]() {
    stepP(B2v.z, B2v.w, B3v.x, B3v.y, B3v.z);
    stepP(B3v.w, B4v.x, B4v.y, B4v.z, B4v.w);
    stepP(A0v.x, A0v.y, A0v.z, A0v.w, A1v.x);
    stepP(A1v.y, A1v.z, A1v.w, A2v.x, A2v.y);
  };

#pragma unroll 1
  for (int ch = 0; ch < NCH; ++ch) {
    const int bo_cur  = (ch & 1) ? XOFF : 0;
    const int bo_next = XOFF - bo_cur;
    if (ch < NCH - 1) {
      *(float4*)&xbuf[wa[0] + bo_next] = st0;
      *(float4*)&xbuf[wa[1] + bo_next] = st1;
      *(float4*)&xbuf[wa[2] + bo_next] = st2;
      *(float4*)&xbuf[wa[3] + bo_next] = st3;
      *(float4*)&xbuf[wa[4] + bo_next] = st4;
    }
    if (ch < NCH - 2) {
      st0 = *gp[0]; gp[0] += 40; st1 = *gp[1]; gp[1] += 40;
      st2 = *gp[2]; gp[2] += 40; st3 = *gp[3]; gp[3] += 40;
      st4 = *gp[4]; gp[4] += 40;
    }
    const int xb = bo_cur + grp * RSTR;
    rdg(xb +   0, A0v, A1v, A2v, A3v, A4v);
    rdg(xb +  20, B0v, B1v, B2v, B3v, B4v);
    SUBA(); rdg(xb +  40, A0v, A1v, A2v, A3v, A4v);
    SUBB(); rdg(xb +  60, B0v, B1v, B2v, B3v, B4v);
    SUBA(); rdg(xb +  80, A0v, A1v, A2v, A3v, A4v);
    SUBB(); rdg(xb + 100, B0v, B1v, B2v, B3v, B4v);
    SUBA(); rdg(xb + 120, A0v, A1v, A2v, A3v, A4v);
    SUBB(); rdg(xb + 140, B0v, B1v, B2v, B3v, B4v);
    SUBA();
    // cross-chunk: next chunk's first group (dead values for last chunk)
    rdg(bo_next + grp * RSTR, A0v, A1v, A2v, A3v, A4v);
    SUBB();
  }

  // ---- MLP head (single wave; no barriers needed) ----
  float in5_0 = hv0 + xl0, in5_1 = hv1 + xl1, in5_2 = hv2 + xl2,
        in5_3 = hv3 + xl3, in5_4 = hv4 + xl4;

#pragma unroll
  for (int p = 0; p < 4; ++p) {
    int m = p * 8 + j;
    float acc = b1[m];
    acc = fmaf(W1[m * 5 + 0], in5_0, acc);
    acc = fmaf(W1[m * 5 + 1], in5_1, acc);
    acc = fmaf(W1[m * 5 + 2], in5_2, acc);
    acc = fmaf(W1[m * 5 + 3], in5_3, acc);
    acc = fmaf(W1[m * 5 + 4], in5_4, acc);
    s1[grp][m] = fmaxf(acc, 0.0f);
  }
  float y1[32];
#pragma unroll
  for (int k = 0; k < 32; ++k) y1[k] = s1[grp][k];

  auto dot32 = [&](const float* W, int m, const float* y, float b) {
    float acc = b;
    const float4* w4 = (const float4*)(W + m * 32);
#pragma unroll
    for (int k4 = 0; k4 < 8; ++k4) {
      float4 w = w4[k4];
      acc = fmaf(w.x, y[k4 * 4 + 0], acc);
      acc = fmaf(w.y, y[k4 * 4 + 1], acc);
      acc = fmaf(w.z, y[k4 * 4 + 2], acc);
      acc = fmaf(w.w, y[k4 * 4 + 3], acc);
    }
    return acc;
  };

#pragma unroll
  for (int p = 0; p < 4; ++p) {
    int m = p * 8 + j;
    s2[grp][m] = fmaxf(dot32(W2, m, y1, b2[m]), 0.0f);
  }
  float y2[32];
#pragma unroll
  for (int k = 0; k < 32; ++k) y2[k] = s2[grp][k];

  if (act) out[row * HD + j] = dot32(W3, j, y2, b3[j]);
}

extern "C" void kernel_launch(void* const* d_in, const int* in_sizes, int n_in,
                              void* d_out, int out_size, void* d_ws, size_t ws_size,
                              hipStream_t stream) {
  const float* x   = (const float*)d_in[0];
  const float* Wih = (const float*)d_in[1];
  const float* Whh = (const float*)d_in[2];
  const float* bih = (const float*)d_in[3];
  const float* bhh = (const float*)d_in[4];
  const float* W1  = (const float*)d_in[5];
  const float* b1  = (const float*)d_in[6];
  const float* W2  = (const float*)d_in[7];
  const float* b2  = (const float*)d_in[8];
  const float* W3  = (const float*)d_in[9];
  const float* b3  = (const float*)d_in[10];

  int B = in_sizes[0] / (TT * HD);
  int grid = (B + RPB - 1) / RPB;
  hipLaunchKernelGGL(lstm_mlp_kernel, dim3(grid), dim3(64), 0, stream,
                     x, Wih, Whh, bih, bhh, W1, b1, W2, b2, W3, b3,
                     (float*)d_out, B);
}

// Round 6
// 217.209 us; speedup vs baseline: 1.0364x; 1.0364x over previous
//
#include <hip/hip_runtime.h>

// LSTM (B=8192, T=512, H=5) + MLP 5->32->32->5, fp32.
// Round 15: R13 exactly, with the 3 hw rcps -> bit-seed + 3-Newton FMA
// inverses (no sign games, no cndmask — those were R14's +102 busy).
//  - Evidence: R9-R13 wall ~485 = busy ~325 + exposed ~160 (4 serial
//    trans regions x ~40); trans issue ~23 cyc each x 8 = ~185 of busy.
//    R14 showed exposed stays ~constant per region and that select-based
//    gate recovery explodes issue. So: cut trans COUNT (8->5) with a
//    drop-in replacement that keeps R13's dataflow byte-identical.
//  - finv(A): r0 = bitcast(0x7EF311C3 - bits(A)) (~5% rel err, any
//    positive normal, exponent-symmetric -> works for m02 in [1,1e12]
//    and Ac in [1,2]); 3 Newtons -> ~4e-11 rel err (= hrcp class).
//    7 pure-FMA ops, chain ~35, fillable by the existing F2/F3 blocks.
//  - Keeps: fences + 2-deep zx pipeline (R13), rcp-combines (R13),
//    freed allocator (R10), DPP broadcast (R9), LDS x-staging RSTR=164
//    (R8), pre-folded activation scales (R7).

#define LOG2E 1.44269504088896f

__device__ __forceinline__ float hexp2(float x) { return __builtin_amdgcn_exp2f(x); }
#define SBAR() __builtin_amdgcn_sched_barrier(0)

// reciprocal via bit-trick seed + 3 Newton iterations: pure FMA, no trans.
// seed rel err ~5% for any positive normal; after 3 Newtons ~4e-11.
__device__ __forceinline__ float finv(float A) {
  int i = 0x7EF311C3 - __builtin_bit_cast(int, A);
  float r = __builtin_bit_cast(float, i);
  r = r * fmaf(-A, r, 2.0f);
  r = r * fmaf(-A, r, 2.0f);
  r = r * fmaf(-A, r, 2.0f);
  return r;
}

template<int CTRL>
__device__ __forceinline__ float dpp_mov(float x) {
  int r = __builtin_amdgcn_update_dpp(0, __builtin_bit_cast(int, x),
                                      CTRL, 0xF, 0xF, true);
  return __builtin_bit_cast(float, r);
}
template<int CTRL, int BANKMASK>
__device__ __forceinline__ float dpp_merge(float old, float src) {
  int r = __builtin_amdgcn_update_dpp(__builtin_bit_cast(int, old),
                                      __builtin_bit_cast(int, src),
                                      CTRL, 0xF, BANKMASK, false);
  return __builtin_bit_cast(float, r);
}

constexpr int TT   = 512;
constexpr int HD   = 5;
constexpr int RPB  = 8;     // rows per wave (8 lanes each)
constexpr int CHNK = 32;    // steps per LDS chunk
constexpr int RSTR = 164;   // padded LDS row stride
constexpr int XOFF = RPB * RSTR;
constexpr int NCH  = TT / CHNK;

__global__ __attribute__((amdgpu_flat_work_group_size(64, 64),
                          amdgpu_waves_per_eu(1, 1)))
void lstm_mlp_kernel(
    const float* __restrict__ x,   const float* __restrict__ Wih,
    const float* __restrict__ Whh, const float* __restrict__ bih,
    const float* __restrict__ bhh, const float* __restrict__ W1,
    const float* __restrict__ b1,  const float* __restrict__ W2,
    const float* __restrict__ b2,  const float* __restrict__ W3,
    const float* __restrict__ b3,  float* __restrict__ out, int B)
{
  const int lane = threadIdx.x;
  const int grp  = lane >> 3;           // row within block (0..7)
  const int j    = lane & 7;            // unit owned (valid if j<5)
  const int jj   = (j < 5) ? j : 0;
  const int blockRow = blockIdx.x * RPB;
  const int row  = blockRow + grp;
  const bool act = (j < 5) && (row < B);

  __shared__ __align__(16) float xbuf[2 * XOFF];
  __shared__ float s1[RPB][32];
  __shared__ float s2[RPB][32];

  // ---- per-lane weights (rows {j,5+j,10+j,15+j}), activation pre-scaled --
  float wih[4][5], whh[4][5], bsum[4];
#pragma unroll
  for (int G = 0; G < 4; ++G) {
    const float sc = (G == 2) ? (2.0f * LOG2E) : (-LOG2E);
#pragma unroll
    for (int k = 0; k < 5; ++k) {
      wih[G][k] = Wih[(G * 5 + jj) * 5 + k] * sc;
      whh[G][k] = Whh[(G * 5 + jj) * 5 + k] * sc;
    }
    bsum[G] = (bih[G * 5 + jj] + bhh[G * 5 + jj]) * sc;
  }

  const int rowc = (row < B) ? row : (B - 1);
  const float xl0 = x[(size_t)rowc * (TT * HD) + 511 * HD + 0];
  const float xl1 = x[(size_t)rowc * (TT * HD) + 511 * HD + 1];
  const float xl2 = x[(size_t)rowc * (TT * HD) + 511 * HD + 2];
  const float xl3 = x[(size_t)rowc * (TT * HD) + 511 * HD + 3];
  const float xl4 = x[(size_t)rowc * (TT * HD) + 511 * HD + 4];

  // ---- staging: 5x16B per lane per 32-step chunk (R8-proven) ----
  const float4* gp[5];
  int wa[5];
#pragma unroll
  for (int i = 0; i < 5; ++i) {
    int u  = i * 64 + lane;
    int r  = u / 40;
    int o4 = u - r * 40;
    int gr = blockRow + r; if (gr >= B) gr = B - 1;
    gp[i]  = (const float4*)(x + (size_t)gr * (TT * HD)) + o4;
    wa[i]  = r * RSTR + o4 * 4;
  }

  float4 st0, st1, st2, st3, st4;
  st0 = *gp[0]; gp[0] += 40; st1 = *gp[1]; gp[1] += 40;
  st2 = *gp[2]; gp[2] += 40; st3 = *gp[3]; gp[3] += 40;
  st4 = *gp[4]; gp[4] += 40;
  *(float4*)&xbuf[wa[0]] = st0; *(float4*)&xbuf[wa[1]] = st1;
  *(float4*)&xbuf[wa[2]] = st2; *(float4*)&xbuf[wa[3]] = st3;
  *(float4*)&xbuf[wa[4]] = st4;
  st0 = *gp[0]; gp[0] += 40; st1 = *gp[1]; gp[1] += 40;
  st2 = *gp[2]; gp[2] += 40; st3 = *gp[3]; gp[3] += 40;
  st4 = *gp[4]; gp[4] += 40;

  // ---- recurrence state ----
  float c = 0.0f;
  float hv0 = 0.f, hv1 = 0.f, hv2 = 0.f, hv3 = 0.f, hv4 = 0.f;
  // 2-deep x-part queue: zxA = current step, zxB = next step
  float zxA0, zxA1, zxA2, zxA3;
  float zxB0, zxB1, zxB2, zxB3;

  // prologue: zx for steps 0 and 1 from the just-written chunk-0 buffer
  {
    const float* xp = &xbuf[grp * RSTR];
#pragma unroll
    for (int s = 0; s < 2; ++s) {
      float p0 = xp[5*s+0], p1 = xp[5*s+1], p2 = xp[5*s+2],
            p3 = xp[5*s+3], p4 = xp[5*s+4];
      float t0 = bsum[0], t1 = bsum[1], t2 = bsum[2], t3 = bsum[3];
      t0 = fmaf(p0, wih[0][0], t0); t0 = fmaf(p1, wih[0][1], t0);
      t0 = fmaf(p2, wih[0][2], t0); t0 = fmaf(p3, wih[0][3], t0);
      t0 = fmaf(p4, wih[0][4], t0);
      t1 = fmaf(p0, wih[1][0], t1); t1 = fmaf(p1, wih[1][1], t1);
      t1 = fmaf(p2, wih[1][2], t1); t1 = fmaf(p3, wih[1][3], t1);
      t1 = fmaf(p4, wih[1][4], t1);
      t2 = fmaf(p0, wih[2][0], t2); t2 = fmaf(p1, wih[2][1], t2);
      t2 = fmaf(p2, wih[2][2], t2); t2 = fmaf(p3, wih[2][3], t2);
      t2 = fmaf(p4, wih[2][4], t2);
      t3 = fmaf(p0, wih[3][0], t3); t3 = fmaf(p1, wih[3][1], t3);
      t3 = fmaf(p2, wih[3][2], t3); t3 = fmaf(p3, wih[3][3], t3);
      t3 = fmaf(p4, wih[3][4], t3);
      if (s == 0) { zxA0 = t0; zxA1 = t1; zxA2 = t2; zxA3 = t3; }
      else        { zxB0 = t0; zxB1 = t1; zxB2 = t2; zxB3 = t3; }
    }
  }

  // fenced pipelined step: consumes zxA (step t), computes x-part of
  // step t+2 from n0..n4 inside t's latency windows.
  auto stepP = [&](float n0, float n1, float n2, float n3, float n4) {
    // P1: h-dots (chain head), order bias->x (in zx) ->h0..h4 preserved
    float z0 = zxA0, z1 = zxA1, z2 = zxA2, z3 = zxA3;
    z0 = fmaf(hv0, whh[0][0], z0); z0 = fmaf(hv1, whh[0][1], z0);
    z0 = fmaf(hv2, whh[0][2], z0); z0 = fmaf(hv3, whh[0][3], z0);
    z0 = fmaf(hv4, whh[0][4], z0);
    z1 = fmaf(hv0, whh[1][0], z1); z1 = fmaf(hv1, whh[1][1], z1);
    z1 = fmaf(hv2, whh[1][2], z1); z1 = fmaf(hv3, whh[1][3], z1);
    z1 = fmaf(hv4, whh[1][4], z1);
    z2 = fmaf(hv0, whh[2][0], z2); z2 = fmaf(hv1, whh[2][1], z2);
    z2 = fmaf(hv2, whh[2][2], z2); z2 = fmaf(hv3, whh[2][3], z2);
    z2 = fmaf(hv4, whh[2][4], z2);
    z3 = fmaf(hv0, whh[3][0], z3); z3 = fmaf(hv1, whh[3][1], z3);
    z3 = fmaf(hv2, whh[3][2], z3); z3 = fmaf(hv3, whh[3][3], z3);
    z3 = fmaf(hv4, whh[3][4], z3);
    // P2: exps, g-gate first (it heads the c-chain)
    float e2 = hexp2(z2);
    float e0 = hexp2(z0);
    float e1 = hexp2(z1);
    float e3 = hexp2(z3);
    SBAR();
    // F1: x-part(t+2) gates 0,1 — fills exp latency
    float n_0 = bsum[0];
    n_0 = fmaf(n0, wih[0][0], n_0); n_0 = fmaf(n1, wih[0][1], n_0);
    n_0 = fmaf(n2, wih[0][2], n_0); n_0 = fmaf(n3, wih[0][3], n_0);
    n_0 = fmaf(n4, wih[0][4], n_0);
    float n_1 = bsum[1];
    n_1 = fmaf(n0, wih[1][0], n_1); n_1 = fmaf(n1, wih[1][1], n_1);
    n_1 = fmaf(n2, wih[1][2], n_1); n_1 = fmaf(n3, wih[1][3], n_1);
    n_1 = fmaf(n4, wih[1][4], n_1);
    SBAR();
    // P3: combined denominators + 2 FMA-inverses (no trans)
    float A2 = 1.0f + e2;
    float A0 = 1.0f + e0;
    float m02 = A0 * A2;
    float r02 = finv(m02);
    float A1 = 1.0f + e1;
    float A3 = 1.0f + e3;
    float m13 = A1 * A3;
    float r13 = finv(m13);
    SBAR();
    // F2: x-part(t+2) gate 2 — fills inv chain
    float n_2 = bsum[2];
    n_2 = fmaf(n0, wih[2][0], n_2); n_2 = fmaf(n1, wih[2][1], n_2);
    n_2 = fmaf(n2, wih[2][2], n_2); n_2 = fmaf(n3, wih[2][3], n_2);
    n_2 = fmaf(n4, wih[2][4], n_2);
    SBAR();
    // P4: gates + c-update + exp2(c)
    float t2g = A2 - 2.0f;
    float ig  = t2g * r02;        // i*g
    float fg  = A3 * r13;         // f
    float og  = A1 * r13;         // o
    c = fmaf(fg, c, ig);
    float ec = hexp2(c * (2.0f * LOG2E));
    SBAR();
    // F3: x-part(t+2) gate 3 + 2*o — fills exp2(c) latency
    float n_3 = bsum[3];
    n_3 = fmaf(n0, wih[3][0], n_3); n_3 = fmaf(n1, wih[3][1], n_3);
    n_3 = fmaf(n2, wih[3][2], n_3); n_3 = fmaf(n3, wih[3][3], n_3);
    n_3 = fmaf(n4, wih[3][4], n_3);
    float o2 = og + og;
    SBAR();
    // P5: tanh(c) via FMA-inverse
    float Ac = 1.0f + ec;
    float rc = finv(Ac);
    // P6: h and broadcast (chain tail)
    float h = fmaf(-o2, rc, og);
    float q0 = dpp_mov<0x00>(h);
    float q1 = dpp_mov<0x55>(h);
    float q2 = dpp_mov<0xAA>(h);
    float q3 = dpp_mov<0xFF>(h);
    hv0 = dpp_merge<0x114, 0xA>(q0, q0);
    hv1 = dpp_merge<0x114, 0xA>(q1, q1);
    hv2 = dpp_merge<0x114, 0xA>(q2, q2);
    hv3 = dpp_merge<0x114, 0xA>(q3, q3);
    hv4 = dpp_merge<0x104, 0x5>(q0, q0);
    // rotate the zx queue
    zxA0 = zxB0; zxA1 = zxB1; zxA2 = zxB2; zxA3 = zxB3;
    zxB0 = n_0;  zxB1 = n_1;  zxB2 = n_2;  zxB3 = n_3;
  };

  float4 A0v, A1v, A2v, A3v, A4v;
  float4 B0v, B1v, B2v, B3v, B4v;

  auto rdg = [&](int fi, float4& Av, float4& Bv, float4& Cv, float4& Dv, float4& Ev) {
    const float4* p = (const float4*)&xbuf[fi];
    Av = p[0]; Bv = p[1]; Cv = p[2]; Dv = p[3]; Ev = p[4];
  };

  // SUBA: steps a..a+3; fillers = x(a+2..a+5)
  auto SUBA = [&]() {
    stepP(A2v.z, A2v.w, A3v.x, A3v.y, A3v.z);
    stepP(A3v.w, A4v.x, A4v.y, A4v.z, A4v.w);
    stepP(B0v.x, B0v.y, B0v.z, B0v.w, B1v.x);
    stepP(B1v.y, B1v.z, B1v.w, B2v.x, B2v.y);
  };
  // SUBB: steps b..b+3; fillers = x(b+2..b+5)
  auto SUBB = [&]() {
    stepP(B2v.z, B2v.w, B3v.x, B3v.y, B3v.z);
    stepP(B3v.w, B4v.x, B4v.y, B4v.z, B4v.w);
    stepP(A0v.x, A0v.y, A0v.z, A0v.w, A1v.x);
    stepP(A1v.y, A1v.z, A1v.w, A2v.x, A2v.y);
  };

#pragma unroll 1
  for (int ch = 0; ch < NCH; ++ch) {
    const int bo_cur  = (ch & 1) ? XOFF : 0;
    const int bo_next = XOFF - bo_cur;
    if (ch < NCH - 1) {
      *(float4*)&xbuf[wa[0] + bo_next] = st0;
      *(float4*)&xbuf[wa[1] + bo_next] = st1;
      *(float4*)&xbuf[wa[2] + bo_next] = st2;
      *(float4*)&xbuf[wa[3] + bo_next] = st3;
      *(float4*)&xbuf[wa[4] + bo_next] = st4;
    }
    if (ch < NCH - 2) {
      st0 = *gp[0]; gp[0] += 40; st1 = *gp[1]; gp[1] += 40;
      st2 = *gp[2]; gp[2] += 40; st3 = *gp[3]; gp[3] += 40;
      st4 = *gp[4]; gp[4] += 40;
    }
    const int xb = bo_cur + grp * RSTR;
    rdg(xb +   0, A0v, A1v, A2v, A3v, A4v);
    rdg(xb +  20, B0v, B1v, B2v, B3v, B4v);
    SUBA(); rdg(xb +  40, A0v, A1v, A2v, A3v, A4v);
    SUBB(); rdg(xb +  60, B0v, B1v, B2v, B3v, B4v);
    SUBA(); rdg(xb +  80, A0v, A1v, A2v, A3v, A4v);
    SUBB(); rdg(xb + 100, B0v, B1v, B2v, B3v, B4v);
    SUBA(); rdg(xb + 120, A0v, A1v, A2v, A3v, A4v);
    SUBB(); rdg(xb + 140, B0v, B1v, B2v, B3v, B4v);
    SUBA();
    // cross-chunk: next chunk's first group (dead values for last chunk)
    rdg(bo_next + grp * RSTR, A0v, A1v, A2v, A3v, A4v);
    SUBB();
  }

  // ---- MLP head (single wave; no barriers needed) ----
  float in5_0 = hv0 + xl0, in5_1 = hv1 + xl1, in5_2 = hv2 + xl2,
        in5_3 = hv3 + xl3, in5_4 = hv4 + xl4;

#pragma unroll
  for (int p = 0; p < 4; ++p) {
    int m = p * 8 + j;
    float acc = b1[m];
    acc = fmaf(W1[m * 5 + 0], in5_0, acc);
    acc = fmaf(W1[m * 5 + 1], in5_1, acc);
    acc = fmaf(W1[m * 5 + 2], in5_2, acc);
    acc = fmaf(W1[m * 5 + 3], in5_3, acc);
    acc = fmaf(W1[m * 5 + 4], in5_4, acc);
    s1[grp][m] = fmaxf(acc, 0.0f);
  }
  float y1[32];
#pragma unroll
  for (int k = 0; k < 32; ++k) y1[k] = s1[grp][k];

  auto dot32 = [&](const float* W, int m, const float* y, float b) {
    float acc = b;
    const float4* w4 = (const float4*)(W + m * 32);
#pragma unroll
    for (int k4 = 0; k4 < 8; ++k4) {
      float4 w = w4[k4];
      acc = fmaf(w.x, y[k4 * 4 + 0], acc);
      acc = fmaf(w.y, y[k4 * 4 + 1], acc);
      acc = fmaf(w.z, y[k4 * 4 + 2], acc);
      acc = fmaf(w.w, y[k4 * 4 + 3], acc);
    }
    return acc;
  };

#pragma unroll
  for (int p = 0; p < 4; ++p) {
    int m = p * 8 + j;
    s2[grp][m] = fmaxf(dot32(W2, m, y1, b2[m]), 0.0f);
  }
  float y2[32];
#pragma unroll
  for (int k = 0; k < 32; ++k) y2[k] = s2[grp][k];

  if (act) out[row * HD + j] = dot32(W3, j, y2, b3[j]);
}

extern "C" void kernel_launch(void* const* d_in, const int* in_sizes, int n_in,
                              void* d_out, int out_size, void* d_ws, size_t ws_size,
                              hipStream_t stream) {
  const float* x   = (const float*)d_in[0];
  const float* Wih = (const float*)d_in[1];
  const float* Whh = (const float*)d_in[2];
  const float* bih = (const float*)d_in[3];
  const float* bhh = (const float*)d_in[4];
  const float* W1  = (const float*)d_in[5];
  const float* b1  = (const float*)d_in[6];
  const float* W2  = (const float*)d_in[7];
  const float* b2  = (const float*)d_in[8];
  const float* W3  = (const float*)d_in[9];
  const float* b3  = (const float*)d_in[10];

  int B = in_sizes[0] / (TT * HD);
  int grid = (B + RPB - 1) / RPB;
  hipLaunchKernelGGL(lstm_mlp_kernel, dim3(grid), dim3(64), 0, stream,
                     x, Wih, Whh, bih, bhh, W1, b1, W2, b2, W3, b3,
                     (float*)d_out, B);
}

// Round 7
// 191.430 us; speedup vs baseline: 1.1760x; 1.1347x over previous
//
#include <hip/hip_runtime.h>

// LSTM (B=8192, T=512, H=5) + MLP 5->32->32->5, fp32.
// Round 16: R13 structure + packed-FP32 dots (v_pk_fma_f32).
//  - R14/R15 post-mortem: hw trans are CHEAP (~4-8 busy cyc); replacing
//    them with FMA chains added ~4 cyc/inst. hrcp restored (R13-proven).
//  - Model fitting R9-R15: wall ~= busy + ~165 (invariant), and
//    Δwall ~= +-3.5 cyc per instruction. Only instruction count moves
//    the wall. R13 floor: ~68 inst/step, 40 of them dot-product FMAs.
//  - Lever: MI355X FP32 peak (157.3 TF) = 2x scalar rate via VOP3P
//    v_pk_fma_f32. Pair gates: (z0,z1) += hv_k*(w0k,w1k), (z2,z3)
//    likewise; same for the x-part fillers. 40 -> 20 insts, bit-exact
//    per-gate FP order (IEEE fma per half). Expressed with
//    __builtin_elementwise_fma on float-ext_vector(2): packs on
//    gfx950, falls back to 2 scalar fma worst-case (= R13, no loss).
//  - A/B step alternation: step t consumes AND refills the same zx
//    slot (t+2 lands where t was read) -> zx queue rotation is free.
//  - Keeps: fences + 2-deep zx pipeline (R13), rcp-combines (R13),
//    freed allocator (R10), DPP broadcast (R9), LDS x-staging RSTR=164
//    (R8), pre-folded activation scales (R7).

#define LOG2E 1.44269504088896f

typedef float f32x2 __attribute__((ext_vector_type(2)));

__device__ __forceinline__ float hexp2(float x) { return __builtin_amdgcn_exp2f(x); }
__device__ __forceinline__ float hrcp(float x)  { return __builtin_amdgcn_rcpf(x); }
#define SBAR() __builtin_amdgcn_sched_barrier(0)

// packed fma with scalar-splat multiplicand: d = (a,a)*b + c
__device__ __forceinline__ f32x2 pk2(float a, f32x2 b, f32x2 c) {
  f32x2 av; av.x = a; av.y = a;
  return __builtin_elementwise_fma(av, b, c);
}

template<int CTRL>
__device__ __forceinline__ float dpp_mov(float x) {
  int r = __builtin_amdgcn_update_dpp(0, __builtin_bit_cast(int, x),
                                      CTRL, 0xF, 0xF, true);
  return __builtin_bit_cast(float, r);
}
template<int CTRL, int BANKMASK>
__device__ __forceinline__ float dpp_merge(float old, float src) {
  int r = __builtin_amdgcn_update_dpp(__builtin_bit_cast(int, old),
                                      __builtin_bit_cast(int, src),
                                      CTRL, 0xF, BANKMASK, false);
  return __builtin_bit_cast(float, r);
}

constexpr int TT   = 512;
constexpr int HD   = 5;
constexpr int RPB  = 8;     // rows per wave (8 lanes each)
constexpr int CHNK = 32;    // steps per LDS chunk
constexpr int RSTR = 164;   // padded LDS row stride
constexpr int XOFF = RPB * RSTR;
constexpr int NCH  = TT / CHNK;

__global__ __attribute__((amdgpu_flat_work_group_size(64, 64),
                          amdgpu_waves_per_eu(1, 1)))
void lstm_mlp_kernel(
    const float* __restrict__ x,   const float* __restrict__ Wih,
    const float* __restrict__ Whh, const float* __restrict__ bih,
    const float* __restrict__ bhh, const float* __restrict__ W1,
    const float* __restrict__ b1,  const float* __restrict__ W2,
    const float* __restrict__ b2,  const float* __restrict__ W3,
    const float* __restrict__ b3,  float* __restrict__ out, int B)
{
  const int lane = threadIdx.x;
  const int grp  = lane >> 3;           // row within block (0..7)
  const int j    = lane & 7;            // unit owned (valid if j<5)
  const int jj   = (j < 5) ? j : 0;
  const int blockRow = blockIdx.x * RPB;
  const int row  = blockRow + grp;
  const bool act = (j < 5) && (row < B);

  __shared__ __align__(16) float xbuf[2 * XOFF];
  __shared__ float s1[RPB][32];
  __shared__ float s2[RPB][32];

  // ---- per-lane weights, gate-PAIRED (x=gate0/2, y=gate1/3), pre-scaled --
  f32x2 wih01[5], wih23[5], whh01[5], whh23[5], bsum01, bsum23;
  {
    const float sA = -LOG2E, sG = 2.0f * LOG2E;
#pragma unroll
    for (int k = 0; k < 5; ++k) {
      wih01[k].x = Wih[(0 * 5 + jj) * 5 + k] * sA;
      wih01[k].y = Wih[(1 * 5 + jj) * 5 + k] * sA;
      wih23[k].x = Wih[(2 * 5 + jj) * 5 + k] * sG;
      wih23[k].y = Wih[(3 * 5 + jj) * 5 + k] * sA;
      whh01[k].x = Whh[(0 * 5 + jj) * 5 + k] * sA;
      whh01[k].y = Whh[(1 * 5 + jj) * 5 + k] * sA;
      whh23[k].x = Whh[(2 * 5 + jj) * 5 + k] * sG;
      whh23[k].y = Whh[(3 * 5 + jj) * 5 + k] * sA;
    }
    bsum01.x = (bih[0 * 5 + jj] + bhh[0 * 5 + jj]) * sA;
    bsum01.y = (bih[1 * 5 + jj] + bhh[1 * 5 + jj]) * sA;
    bsum23.x = (bih[2 * 5 + jj] + bhh[2 * 5 + jj]) * sG;
    bsum23.y = (bih[3 * 5 + jj] + bhh[3 * 5 + jj]) * sA;
  }

  const int rowc = (row < B) ? row : (B - 1);
  const float xl0 = x[(size_t)rowc * (TT * HD) + 511 * HD + 0];
  const float xl1 = x[(size_t)rowc * (TT * HD) + 511 * HD + 1];
  const float xl2 = x[(size_t)rowc * (TT * HD) + 511 * HD + 2];
  const float xl3 = x[(size_t)rowc * (TT * HD) + 511 * HD + 3];
  const float xl4 = x[(size_t)rowc * (TT * HD) + 511 * HD + 4];

  // ---- staging: 5x16B per lane per 32-step chunk (R8-proven) ----
  const float4* gp[5];
  int wa[5];
#pragma unroll
  for (int i = 0; i < 5; ++i) {
    int u  = i * 64 + lane;
    int r  = u / 40;
    int o4 = u - r * 40;
    int gr = blockRow + r; if (gr >= B) gr = B - 1;
    gp[i]  = (const float4*)(x + (size_t)gr * (TT * HD)) + o4;
    wa[i]  = r * RSTR + o4 * 4;
  }

  float4 st0, st1, st2, st3, st4;
  st0 = *gp[0]; gp[0] += 40; st1 = *gp[1]; gp[1] += 40;
  st2 = *gp[2]; gp[2] += 40; st3 = *gp[3]; gp[3] += 40;
  st4 = *gp[4]; gp[4] += 40;
  *(float4*)&xbuf[wa[0]] = st0; *(float4*)&xbuf[wa[1]] = st1;
  *(float4*)&xbuf[wa[2]] = st2; *(float4*)&xbuf[wa[3]] = st3;
  *(float4*)&xbuf[wa[4]] = st4;
  st0 = *gp[0]; gp[0] += 40; st1 = *gp[1]; gp[1] += 40;
  st2 = *gp[2]; gp[2] += 40; st3 = *gp[3]; gp[3] += 40;
  st4 = *gp[4]; gp[4] += 40;

  // ---- recurrence state ----
  float c = 0.0f;
  float hv0 = 0.f, hv1 = 0.f, hv2 = 0.f, hv3 = 0.f, hv4 = 0.f;
  // 2-deep x-part queue (paired): A = even steps, B = odd steps
  f32x2 zxA01, zxA23, zxB01, zxB23;

  // prologue: zx for steps 0 (->A) and 1 (->B) from chunk-0 buffer
  {
    const float* xp = &xbuf[grp * RSTR];
    zxA01 = bsum01; zxA23 = bsum23;
    zxA01 = pk2(xp[0], wih01[0], zxA01); zxA01 = pk2(xp[1], wih01[1], zxA01);
    zxA01 = pk2(xp[2], wih01[2], zxA01); zxA01 = pk2(xp[3], wih01[3], zxA01);
    zxA01 = pk2(xp[4], wih01[4], zxA01);
    zxA23 = pk2(xp[0], wih23[0], zxA23); zxA23 = pk2(xp[1], wih23[1], zxA23);
    zxA23 = pk2(xp[2], wih23[2], zxA23); zxA23 = pk2(xp[3], wih23[3], zxA23);
    zxA23 = pk2(xp[4], wih23[4], zxA23);
    zxB01 = bsum01; zxB23 = bsum23;
    zxB01 = pk2(xp[5], wih01[0], zxB01); zxB01 = pk2(xp[6], wih01[1], zxB01);
    zxB01 = pk2(xp[7], wih01[2], zxB01); zxB01 = pk2(xp[8], wih01[3], zxB01);
    zxB01 = pk2(xp[9], wih01[4], zxB01);
    zxB23 = pk2(xp[5], wih23[0], zxB23); zxB23 = pk2(xp[6], wih23[1], zxB23);
    zxB23 = pk2(xp[7], wih23[2], zxB23); zxB23 = pk2(xp[8], wih23[3], zxB23);
    zxB23 = pk2(xp[9], wih23[4], zxB23);
  }

  // fenced pipelined step: consumes zx (step t) and REFILLS the same
  // slot with the x-part of step t+2 (consumed two steps later).
  auto stepCore = [&](f32x2& zx01, f32x2& zx23,
                      float n0, float n1, float n2, float n3, float n4) {
    // P1: h-dots (chain head), packed across gate pairs; per-gate FP
    // order preserved (bias -> x0..x4 (in zx) -> h0..h4)
    f32x2 z01 = zx01, z23 = zx23;
    z01 = pk2(hv0, whh01[0], z01); z01 = pk2(hv1, whh01[1], z01);
    z01 = pk2(hv2, whh01[2], z01); z01 = pk2(hv3, whh01[3], z01);
    z01 = pk2(hv4, whh01[4], z01);
    z23 = pk2(hv0, whh23[0], z23); z23 = pk2(hv1, whh23[1], z23);
    z23 = pk2(hv2, whh23[2], z23); z23 = pk2(hv3, whh23[3], z23);
    z23 = pk2(hv4, whh23[4], z23);
    // P2: exps, g-gate first (it heads the c-chain)
    float e2 = hexp2(z23.x);
    float e0 = hexp2(z01.x);
    float e1 = hexp2(z01.y);
    float e3 = hexp2(z23.y);
    SBAR();
    // F1: x-part(t+2) gates 0,1 (packed) — fills exp latency
    f32x2 n01 = bsum01;
    n01 = pk2(n0, wih01[0], n01); n01 = pk2(n1, wih01[1], n01);
    n01 = pk2(n2, wih01[2], n01); n01 = pk2(n3, wih01[3], n01);
    n01 = pk2(n4, wih01[4], n01);
    SBAR();
    // P3: combined denominators + 2 rcps (R13-proven)
    float A2 = 1.0f + e2;
    float A0 = 1.0f + e0;
    float m02 = A0 * A2;
    float r02 = hrcp(m02);
    float A1 = 1.0f + e1;
    float A3 = 1.0f + e3;
    float m13 = A1 * A3;
    float r13 = hrcp(m13);
    SBAR();
    // F2: x-part(t+2) gates 2,3 (packed) — fills rcp latency
    f32x2 n23 = bsum23;
    n23 = pk2(n0, wih23[0], n23); n23 = pk2(n1, wih23[1], n23);
    n23 = pk2(n2, wih23[2], n23); n23 = pk2(n3, wih23[3], n23);
    n23 = pk2(n4, wih23[4], n23);
    SBAR();
    // P4: gates + c-update + exp2(c)
    float t2g = A2 - 2.0f;
    float ig  = t2g * r02;        // i*g
    float fg  = A3 * r13;         // f
    float og  = A1 * r13;         // o
    c = fmaf(fg, c, ig);
    float ec = hexp2(c * (2.0f * LOG2E));
    SBAR();
    // F3: 2*o — fills exp2(c) latency
    float o2 = og + og;
    SBAR();
    // P5: tanh(c) rcp
    float Ac = 1.0f + ec;
    float rc = hrcp(Ac);
    // P6: h and broadcast (chain tail)
    float h = fmaf(-o2, rc, og);
    float q0 = dpp_mov<0x00>(h);
    float q1 = dpp_mov<0x55>(h);
    float q2 = dpp_mov<0xAA>(h);
    float q3 = dpp_mov<0xFF>(h);
    hv0 = dpp_merge<0x114, 0xA>(q0, q0);
    hv1 = dpp_merge<0x114, 0xA>(q1, q1);
    hv2 = dpp_merge<0x114, 0xA>(q2, q2);
    hv3 = dpp_merge<0x114, 0xA>(q3, q3);
    hv4 = dpp_merge<0x104, 0x5>(q0, q0);
    // refill the consumed slot with t+2's x-part (no rotation needed)
    zx01 = n01; zx23 = n23;
  };

  float4 A0v, A1v, A2v, A3v, A4v;
  float4 B0v, B1v, B2v, B3v, B4v;

  auto rdg = [&](int fi, float4& Av, float4& Bv, float4& Cv, float4& Dv, float4& Ev) {
    const float4* p = (const float4*)&xbuf[fi];
    Av = p[0]; Bv = p[1]; Cv = p[2]; Dv = p[3]; Ev = p[4];
  };

  // SUBA: steps a..a+3 (phase A,B,A,B); fillers = x(a+2..a+5)
  auto SUBA = [&]() {
    stepCore(zxA01, zxA23, A2v.z, A2v.w, A3v.x, A3v.y, A3v.z);
    stepCore(zxB01, zxB23, A3v.w, A4v.x, A4v.y, A4v.z, A4v.w);
    stepCore(zxA01, zxA23, B0v.x, B0v.y, B0v.z, B0v.w, B1v.x);
    stepCore(zxB01, zxB23, B1v.y, B1v.z, B1v.w, B2v.x, B2v.y);
  };
  // SUBB: steps b..b+3; fillers = x(b+2..b+5)
  auto SUBB = [&]() {
    stepCore(zxA01, zxA23, B2v.z, B2v.w, B3v.x, B3v.y, B3v.z);
    stepCore(zxB01, zxB23, B3v.w, B4v.x, B4v.y, B4v.z, B4v.w);
    stepCore(zxA01, zxA23, A0v.x, A0v.y, A0v.z, A0v.w, A1v.x);
    stepCore(zxB01, zxB23, A1v.y, A1v.z, A1v.w, A2v.x, A2v.y);
  };

#pragma unroll 1
  for (int ch = 0; ch < NCH; ++ch) {
    const int bo_cur  = (ch & 1) ? XOFF : 0;
    const int bo_next = XOFF - bo_cur;
    if (ch < NCH - 1) {
      *(float4*)&xbuf[wa[0] + bo_next] = st0;
      *(float4*)&xbuf[wa[1] + bo_next] = st1;
      *(float4*)&xbuf[wa[2] + bo_next] = st2;
      *(float4*)&xbuf[wa[3] + bo_next] = st3;
      *(float4*)&xbuf[wa[4] + bo_next] = st4;
    }
    if (ch < NCH - 2) {
      st0 = *gp[0]; gp[0] += 40; st1 = *gp[1]; gp[1] += 40;
      st2 = *gp[2]; gp[2] += 40; st3 = *gp[3]; gp[3] += 40;
      st4 = *gp[4]; gp[4] += 40;
    }
    const int xb = bo_cur + grp * RSTR;
    rdg(xb +   0, A0v, A1v, A2v, A3v, A4v);
    rdg(xb +  20, B0v, B1v, B2v, B3v, B4v);
    SUBA(); rdg(xb +  40, A0v, A1v, A2v, A3v, A4v);
    SUBB(); rdg(xb +  60, B0v, B1v, B2v, B3v, B4v);
    SUBA(); rdg(xb +  80, A0v, A1v, A2v, A3v, A4v);
    SUBB(); rdg(xb + 100, B0v, B1v, B2v, B3v, B4v);
    SUBA(); rdg(xb + 120, A0v, A1v, A2v, A3v, A4v);
    SUBB(); rdg(xb + 140, B0v, B1v, B2v, B3v, B4v);
    SUBA();
    // cross-chunk: next chunk's first group (dead values for last chunk)
    rdg(bo_next + grp * RSTR, A0v, A1v, A2v, A3v, A4v);
    SUBB();
  }

  // ---- MLP head (single wave; no barriers needed) ----
  float in5_0 = hv0 + xl0, in5_1 = hv1 + xl1, in5_2 = hv2 + xl2,
        in5_3 = hv3 + xl3, in5_4 = hv4 + xl4;

#pragma unroll
  for (int p = 0; p < 4; ++p) {
    int m = p * 8 + j;
    float acc = b1[m];
    acc = fmaf(W1[m * 5 + 0], in5_0, acc);
    acc = fmaf(W1[m * 5 + 1], in5_1, acc);
    acc = fmaf(W1[m * 5 + 2], in5_2, acc);
    acc = fmaf(W1[m * 5 + 3], in5_3, acc);
    acc = fmaf(W1[m * 5 + 4], in5_4, acc);
    s1[grp][m] = fmaxf(acc, 0.0f);
  }
  float y1[32];
#pragma unroll
  for (int k = 0; k < 32; ++k) y1[k] = s1[grp][k];

  auto dot32 = [&](const float* W, int m, const float* y, float b) {
    float acc = b;
    const float4* w4 = (const float4*)(W + m * 32);
#pragma unroll
    for (int k4 = 0; k4 < 8; ++k4) {
      float4 w = w4[k4];
      acc = fmaf(w.x, y[k4 * 4 + 0], acc);
      acc = fmaf(w.y, y[k4 * 4 + 1], acc);
      acc = fmaf(w.z, y[k4 * 4 + 2], acc);
      acc = fmaf(w.w, y[k4 * 4 + 3], acc);
    }
    return acc;
  };

#pragma unroll
  for (int p = 0; p < 4; ++p) {
    int m = p * 8 + j;
    s2[grp][m] = fmaxf(dot32(W2, m, y1, b2[m]), 0.0f);
  }
  float y2[32];
#pragma unroll
  for (int k = 0; k < 32; ++k) y2[k] = s2[grp][k];

  if (act) out[row * HD + j] = dot32(W3, j, y2, b3[j]);
}

extern "C" void kernel_launch(void* const* d_in, const int* in_sizes, int n_in,
                              void* d_out, int out_size, void* d_ws, size_t ws_size,
                              hipStream_t stream) {
  const float* x   = (const float*)d_in[0];
  const float* Wih = (const float*)d_in[1];
  const float* Whh = (const float*)d_in[2];
  const float* bih = (const float*)d_in[3];
  const float* bhh = (const float*)d_in[4];
  const float* W1  = (const float*)d_in[5];
  const float* b1  = (const float*)d_in[6];
  const float* W2  = (const float*)d_in[7];
  const float* b2  = (const float*)d_in[8];
  const float* W3  = (const float*)d_in[9];
  const float* b3  = (const float*)d_in[10];

  int B = in_sizes[0] / (TT * HD);
  int grid = (B + RPB - 1) / RPB;
  hipLaunchKernelGGL(lstm_mlp_kernel, dim3(grid), dim3(64), 0, stream,
                     x, Wih, Whh, bih, bhh, W1, b1, W2, b2, W3, b3,
                     (float*)d_out, B);
}

// Round 8
// 190.503 us; speedup vs baseline: 1.1817x; 1.0049x over previous
//
#include <hip/hip_runtime.h>

// LSTM (B=8192, T=512, H=5) + MLP 5->32->32->5, fp32.
// Round 17: harvest the R16 win — pack the activation ALU too.
//  - R16 post-mortem: pk_fma engaged, wall 485->424 (busy -79). Law
//    confirmed across R9-R16: wall ~= busy + ~170 (serial chain), and
//    Δwall ~= 3.5-4 cyc/instruction. Keep cutting instructions.
//  - This round: (1) packed activation ALU: A01=e01+1, A23=e23+1,
//    M = A01*A23 = (A0*A2, A1*A3) = (m02,m13) elementwise — 6 insts->3,
//    arithmetic identical. (2) pre-scaled c-state cs=2L*c: igs =
//    fmaf(2L,e2,-2L)*r02, cs = fmaf(fg,cs,igs), ec = exp2(cs) — kills
//    the on-chain c*2L mul. (3) F-blocks interleaved (n01/n23
//    alternating, no internal dep stalls) and rebalanced 4/4/3 so the
//    exp2(cs) window is actually filled.
//  - Keeps: pk dots + A/B zx slots (R16), fences + 2-deep zx pipeline
//    (R13), hrcp (cheap, R15 lesson), freed allocator (R10), DPP
//    broadcast (R9), LDS x-staging RSTR=164 (R8), pre-folded scales (R7).

#define LOG2E 1.44269504088896f

typedef float f32x2 __attribute__((ext_vector_type(2)));

__device__ __forceinline__ float hexp2(float x) { return __builtin_amdgcn_exp2f(x); }
__device__ __forceinline__ float hrcp(float x)  { return __builtin_amdgcn_rcpf(x); }
#define SBAR() __builtin_amdgcn_sched_barrier(0)

// packed fma with scalar-splat multiplicand: d = (a,a)*b + c
__device__ __forceinline__ f32x2 pk2(float a, f32x2 b, f32x2 c) {
  f32x2 av; av.x = a; av.y = a;
  return __builtin_elementwise_fma(av, b, c);
}

template<int CTRL>
__device__ __forceinline__ float dpp_mov(float x) {
  int r = __builtin_amdgcn_update_dpp(0, __builtin_bit_cast(int, x),
                                      CTRL, 0xF, 0xF, true);
  return __builtin_bit_cast(float, r);
}
template<int CTRL, int BANKMASK>
__device__ __forceinline__ float dpp_merge(float old, float src) {
  int r = __builtin_amdgcn_update_dpp(__builtin_bit_cast(int, old),
                                      __builtin_bit_cast(int, src),
                                      CTRL, 0xF, BANKMASK, false);
  return __builtin_bit_cast(float, r);
}

constexpr int TT   = 512;
constexpr int HD   = 5;
constexpr int RPB  = 8;     // rows per wave (8 lanes each)
constexpr int CHNK = 32;    // steps per LDS chunk
constexpr int RSTR = 164;   // padded LDS row stride
constexpr int XOFF = RPB * RSTR;
constexpr int NCH  = TT / CHNK;

__global__ __attribute__((amdgpu_flat_work_group_size(64, 64),
                          amdgpu_waves_per_eu(1, 1)))
void lstm_mlp_kernel(
    const float* __restrict__ x,   const float* __restrict__ Wih,
    const float* __restrict__ Whh, const float* __restrict__ bih,
    const float* __restrict__ bhh, const float* __restrict__ W1,
    const float* __restrict__ b1,  const float* __restrict__ W2,
    const float* __restrict__ b2,  const float* __restrict__ W3,
    const float* __restrict__ b3,  float* __restrict__ out, int B)
{
  const int lane = threadIdx.x;
  const int grp  = lane >> 3;           // row within block (0..7)
  const int j    = lane & 7;            // unit owned (valid if j<5)
  const int jj   = (j < 5) ? j : 0;
  const int blockRow = blockIdx.x * RPB;
  const int row  = blockRow + grp;
  const bool act = (j < 5) && (row < B);

  __shared__ __align__(16) float xbuf[2 * XOFF];
  __shared__ float s1[RPB][32];
  __shared__ float s2[RPB][32];

  // ---- per-lane weights, gate-PAIRED (x=gate0/2, y=gate1/3), pre-scaled --
  f32x2 wih01[5], wih23[5], whh01[5], whh23[5], bsum01, bsum23;
  {
    const float sA = -LOG2E, sG = 2.0f * LOG2E;
#pragma unroll
    for (int k = 0; k < 5; ++k) {
      wih01[k].x = Wih[(0 * 5 + jj) * 5 + k] * sA;
      wih01[k].y = Wih[(1 * 5 + jj) * 5 + k] * sA;
      wih23[k].x = Wih[(2 * 5 + jj) * 5 + k] * sG;
      wih23[k].y = Wih[(3 * 5 + jj) * 5 + k] * sA;
      whh01[k].x = Whh[(0 * 5 + jj) * 5 + k] * sA;
      whh01[k].y = Whh[(1 * 5 + jj) * 5 + k] * sA;
      whh23[k].x = Whh[(2 * 5 + jj) * 5 + k] * sG;
      whh23[k].y = Whh[(3 * 5 + jj) * 5 + k] * sA;
    }
    bsum01.x = (bih[0 * 5 + jj] + bhh[0 * 5 + jj]) * sA;
    bsum01.y = (bih[1 * 5 + jj] + bhh[1 * 5 + jj]) * sA;
    bsum23.x = (bih[2 * 5 + jj] + bhh[2 * 5 + jj]) * sG;
    bsum23.y = (bih[3 * 5 + jj] + bhh[3 * 5 + jj]) * sA;
  }

  const int rowc = (row < B) ? row : (B - 1);
  const float xl0 = x[(size_t)rowc * (TT * HD) + 511 * HD + 0];
  const float xl1 = x[(size_t)rowc * (TT * HD) + 511 * HD + 1];
  const float xl2 = x[(size_t)rowc * (TT * HD) + 511 * HD + 2];
  const float xl3 = x[(size_t)rowc * (TT * HD) + 511 * HD + 3];
  const float xl4 = x[(size_t)rowc * (TT * HD) + 511 * HD + 4];

  // ---- staging: 5x16B per lane per 32-step chunk (R8-proven) ----
  const float4* gp[5];
  int wa[5];
#pragma unroll
  for (int i = 0; i < 5; ++i) {
    int u  = i * 64 + lane;
    int r  = u / 40;
    int o4 = u - r * 40;
    int gr = blockRow + r; if (gr >= B) gr = B - 1;
    gp[i]  = (const float4*)(x + (size_t)gr * (TT * HD)) + o4;
    wa[i]  = r * RSTR + o4 * 4;
  }

  float4 st0, st1, st2, st3, st4;
  st0 = *gp[0]; gp[0] += 40; st1 = *gp[1]; gp[1] += 40;
  st2 = *gp[2]; gp[2] += 40; st3 = *gp[3]; gp[3] += 40;
  st4 = *gp[4]; gp[4] += 40;
  *(float4*)&xbuf[wa[0]] = st0; *(float4*)&xbuf[wa[1]] = st1;
  *(float4*)&xbuf[wa[2]] = st2; *(float4*)&xbuf[wa[3]] = st3;
  *(float4*)&xbuf[wa[4]] = st4;
  st0 = *gp[0]; gp[0] += 40; st1 = *gp[1]; gp[1] += 40;
  st2 = *gp[2]; gp[2] += 40; st3 = *gp[3]; gp[3] += 40;
  st4 = *gp[4]; gp[4] += 40;

  // ---- recurrence state ----
  float cs = 0.0f;   // pre-scaled cell state: cs = 2*LOG2E * c
  float hv0 = 0.f, hv1 = 0.f, hv2 = 0.f, hv3 = 0.f, hv4 = 0.f;
  // 2-deep x-part queue (paired): A = even steps, B = odd steps
  f32x2 zxA01, zxA23, zxB01, zxB23;

  // prologue: zx for steps 0 (->A) and 1 (->B) from chunk-0 buffer
  {
    const float* xp = &xbuf[grp * RSTR];
    zxA01 = bsum01; zxA23 = bsum23;
    zxA01 = pk2(xp[0], wih01[0], zxA01); zxA01 = pk2(xp[1], wih01[1], zxA01);
    zxA01 = pk2(xp[2], wih01[2], zxA01); zxA01 = pk2(xp[3], wih01[3], zxA01);
    zxA01 = pk2(xp[4], wih01[4], zxA01);
    zxA23 = pk2(xp[0], wih23[0], zxA23); zxA23 = pk2(xp[1], wih23[1], zxA23);
    zxA23 = pk2(xp[2], wih23[2], zxA23); zxA23 = pk2(xp[3], wih23[3], zxA23);
    zxA23 = pk2(xp[4], wih23[4], zxA23);
    zxB01 = bsum01; zxB23 = bsum23;
    zxB01 = pk2(xp[5], wih01[0], zxB01); zxB01 = pk2(xp[6], wih01[1], zxB01);
    zxB01 = pk2(xp[7], wih01[2], zxB01); zxB01 = pk2(xp[8], wih01[3], zxB01);
    zxB01 = pk2(xp[9], wih01[4], zxB01);
    zxB23 = pk2(xp[5], wih23[0], zxB23); zxB23 = pk2(xp[6], wih23[1], zxB23);
    zxB23 = pk2(xp[7], wih23[2], zxB23); zxB23 = pk2(xp[8], wih23[3], zxB23);
    zxB23 = pk2(xp[9], wih23[4], zxB23);
  }

  // fenced pipelined step: consumes zx (step t) and REFILLS the same
  // slot with the x-part of step t+2 (consumed two steps later).
  auto stepCore = [&](f32x2& zx01, f32x2& zx23,
                      float n0, float n1, float n2, float n3, float n4) {
    // P1: h-dots (chain head), packed across gate pairs, chains
    // interleaved textually; per-gate FP order preserved.
    f32x2 z01 = zx01, z23 = zx23;
    z01 = pk2(hv0, whh01[0], z01); z23 = pk2(hv0, whh23[0], z23);
    z01 = pk2(hv1, whh01[1], z01); z23 = pk2(hv1, whh23[1], z23);
    z01 = pk2(hv2, whh01[2], z01); z23 = pk2(hv2, whh23[2], z23);
    z01 = pk2(hv3, whh01[3], z01); z23 = pk2(hv3, whh23[3], z23);
    z01 = pk2(hv4, whh01[4], z01); z23 = pk2(hv4, whh23[4], z23);
    // P2: exps into pairs (e01, e23), g-gate first (heads the c-chain)
    f32x2 e01, e23;
    e23.x = hexp2(z23.x);
    e01.x = hexp2(z01.x);
    e01.y = hexp2(z01.y);
    e23.y = hexp2(z23.y);
    SBAR();
    // F1: x-part(t+2), both chains interleaved — fills exp latency
    f32x2 n01 = bsum01, n23 = bsum23;
    n01 = pk2(n0, wih01[0], n01); n23 = pk2(n0, wih23[0], n23);
    n01 = pk2(n1, wih01[1], n01); n23 = pk2(n1, wih23[1], n23);
    SBAR();
    // P3: packed denominators + elementwise cross-product + 2 rcps
    f32x2 one2; one2.x = 1.0f; one2.y = 1.0f;
    f32x2 A01 = e01 + one2;          // (A0, A1)
    f32x2 A23 = e23 + one2;          // (A2, A3)
    f32x2 M   = A01 * A23;           // (A0*A2, A1*A3) = (m02, m13)
    float r02 = hrcp(M.x);
    float r13 = hrcp(M.y);
    float t2g2 = fmaf(2.0f * LOG2E, e23.x, -2.0f * LOG2E); // 2L*(A2-2)
    SBAR();
    // F2: x-part(t+2) — fills rcp latency
    n01 = pk2(n2, wih01[2], n01); n23 = pk2(n2, wih23[2], n23);
    n01 = pk2(n3, wih01[3], n01); n23 = pk2(n3, wih23[3], n23);
    SBAR();
    // P4: gates + pre-scaled c-update + exp2(cs)  [cs = 2L*c]
    float igs = t2g2 * r02;          // 2L * i*g
    float fg  = A23.y * r13;         // f
    float og  = A01.y * r13;         // o
    cs = fmaf(fg, cs, igs);
    float ec = hexp2(cs);
    SBAR();
    // F3: x-part(t+2) tail + 2*o — fills exp2(cs) latency
    n01 = pk2(n4, wih01[4], n01); n23 = pk2(n4, wih23[4], n23);
    float o2 = og + og;
    SBAR();
    // P5: tanh(c) rcp
    float Ac = 1.0f + ec;
    float rc = hrcp(Ac);
    // P6: h and broadcast (chain tail)
    float h = fmaf(-o2, rc, og);
    float q0 = dpp_mov<0x00>(h);
    float q1 = dpp_mov<0x55>(h);
    float q2 = dpp_mov<0xAA>(h);
    float q3 = dpp_mov<0xFF>(h);
    hv0 = dpp_merge<0x114, 0xA>(q0, q0);
    hv1 = dpp_merge<0x114, 0xA>(q1, q1);
    hv2 = dpp_merge<0x114, 0xA>(q2, q2);
    hv3 = dpp_merge<0x114, 0xA>(q3, q3);
    hv4 = dpp_merge<0x104, 0x5>(q0, q0);
    // refill the consumed slot with t+2's x-part (no rotation needed)
    zx01 = n01; zx23 = n23;
  };

  float4 A0v, A1v, A2v, A3v, A4v;
  float4 B0v, B1v, B2v, B3v, B4v;

  auto rdg = [&](int fi, float4& Av, float4& Bv, float4& Cv, float4& Dv, float4& Ev) {
    const float4* p = (const float4*)&xbuf[fi];
    Av = p[0]; Bv = p[1]; Cv = p[2]; Dv = p[3]; Ev = p[4];
  };

  // SUBA: steps a..a+3 (phase A,B,A,B); fillers = x(a+2..a+5)
  auto SUBA = [&]() {
    stepCore(zxA01, zxA23, A2v.z, A2v.w, A3v.x, A3v.y, A3v.z);
    stepCore(zxB01, zxB23, A3v.w, A4v.x, A4v.y, A4v.z, A4v.w);
    stepCore(zxA01, zxA23, B0v.x, B0v.y, B0v.z, B0v.w, B1v.x);
    stepCore(zxB01, zxB23, B1v.y, B1v.z, B1v.w, B2v.x, B2v.y);
  };
  // SUBB: steps b..b+3; fillers = x(b+2..b+5)
  auto SUBB = [&]() {
    stepCore(zxA01, zxA23, B2v.z, B2v.w, B3v.x, B3v.y, B3v.z);
    stepCore(zxB01, zxB23, B3v.w, B4v.x, B4v.y, B4v.z, B4v.w);
    stepCore(zxA01, zxA23, A0v.x, A0v.y, A0v.z, A0v.w, A1v.x);
    stepCore(zxB01, zxB23, A1v.y, A1v.z, A1v.w, A2v.x, A2v.y);
  };

#pragma unroll 1
  for (int ch = 0; ch < NCH; ++ch) {
    const int bo_cur  = (ch & 1) ? XOFF : 0;
    const int bo_next = XOFF - bo_cur;
    if (ch < NCH - 1) {
      *(float4*)&xbuf[wa[0] + bo_next] = st0;
      *(float4*)&xbuf[wa[1] + bo_next] = st1;
      *(float4*)&xbuf[wa[2] + bo_next] = st2;
      *(float4*)&xbuf[wa[3] + bo_next] = st3;
      *(float4*)&xbuf[wa[4] + bo_next] = st4;
    }
    if (ch < NCH - 2) {
      st0 = *gp[0]; gp[0] += 40; st1 = *gp[1]; gp[1] += 40;
      st2 = *gp[2]; gp[2] += 40; st3 = *gp[3]; gp[3] += 40;
      st4 = *gp[4]; gp[4] += 40;
    }
    const int xb = bo_cur + grp * RSTR;
    rdg(xb +   0, A0v, A1v, A2v, A3v, A4v);
    rdg(xb +  20, B0v, B1v, B2v, B3v, B4v);
    SUBA(); rdg(xb +  40, A0v, A1v, A2v, A3v, A4v);
    SUBB(); rdg(xb +  60, B0v, B1v, B2v, B3v, B4v);
    SUBA(); rdg(xb +  80, A0v, A1v, A2v, A3v, A4v);
    SUBB(); rdg(xb + 100, B0v, B1v, B2v, B3v, B4v);
    SUBA(); rdg(xb + 120, A0v, A1v, A2v, A3v, A4v);
    SUBB(); rdg(xb + 140, B0v, B1v, B2v, B3v, B4v);
    SUBA();
    // cross-chunk: next chunk's first group (dead values for last chunk)
    rdg(bo_next + grp * RSTR, A0v, A1v, A2v, A3v, A4v);
    SUBB();
  }

  // ---- MLP head (single wave; no barriers needed) ----
  float in5_0 = hv0 + xl0, in5_1 = hv1 + xl1, in5_2 = hv2 + xl2,
        in5_3 = hv3 + xl3, in5_4 = hv4 + xl4;

#pragma unroll
  for (int p = 0; p < 4; ++p) {
    int m = p * 8 + j;
    float acc = b1[m];
    acc = fmaf(W1[m * 5 + 0], in5_0, acc);
    acc = fmaf(W1[m * 5 + 1], in5_1, acc);
    acc = fmaf(W1[m * 5 + 2], in5_2, acc);
    acc = fmaf(W1[m * 5 + 3], in5_3, acc);
    acc = fmaf(W1[m * 5 + 4], in5_4, acc);
    s1[grp][m] = fmaxf(acc, 0.0f);
  }
  float y1[32];
#pragma unroll
  for (int k = 0; k < 32; ++k) y1[k] = s1[grp][k];

  auto dot32 = [&](const float* W, int m, const float* y, float b) {
    float acc = b;
    const float4* w4 = (const float4*)(W + m * 32);
#pragma unroll
    for (int k4 = 0; k4 < 8; ++k4) {
      float4 w = w4[k4];
      acc = fmaf(w.x, y[k4 * 4 + 0], acc);
      acc = fmaf(w.y, y[k4 * 4 + 1], acc);
      acc = fmaf(w.z, y[k4 * 4 + 2], acc);
      acc = fmaf(w.w, y[k4 * 4 + 3], acc);
    }
    return acc;
  };

#pragma unroll
  for (int p = 0; p < 4; ++p) {
    int m = p * 8 + j;
    s2[grp][m] = fmaxf(dot32(W2, m, y1, b2[m]), 0.0f);
  }
  float y2[32];
#pragma unroll
  for (int k = 0; k < 32; ++k) y2[k] = s2[grp][k];

  if (act) out[row * HD + j] = dot32(W3, j, y2, b3[j]);
}

extern "C" void kernel_launch(void* const* d_in, const int* in_sizes, int n_in,
                              void* d_out, int out_size, void* d_ws, size_t ws_size,
                              hipStream_t stream) {
  const float* x   = (const float*)d_in[0];
  const float* Wih = (const float*)d_in[1];
  const float* Whh = (const float*)d_in[2];
  const float* bih = (const float*)d_in[3];
  const float* bhh = (const float*)d_in[4];
  const float* W1  = (const float*)d_in[5];
  const float* b1  = (const float*)d_in[6];
  const float* W2  = (const float*)d_in[7];
  const float* b2  = (const float*)d_in[8];
  const float* W3  = (const float*)d_in[9];
  const float* b3  = (const float*)d_in[10];

  int B = in_sizes[0] / (TT * HD);
  int grid = (B + RPB - 1) / RPB;
  hipLaunchKernelGGL(lstm_mlp_kernel, dim3(grid), dim3(64), 0, stream,
                     x, Wih, Whh, bih, bhh, W1, b1, W2, b2, W3, b3,
                     (float*)d_out, B);
}